// Round 11
// baseline (140.206 us; speedup 1.0000x reference)
//
#include <hip/hip_runtime.h>
#include <hip/hip_bf16.h>
#include <math.h>

// vec[b,e] = sum_s softmax_s( tanh(theta@w.T [b,:] + h[b,s,:]@u) @ v ) * h[b,s,e]
// B=64, S=2048, E=256, T=100
// R11: barrier-free, LDS-free. One WAVE owns 32 s-rows end-to-end:
//   h tile in A-fragment registers (bf16, 64 VGPR), u streamed from L2
//   (2-deep ring), gate + softmax stats + weighted partial all in-wave
//   (shfl only). 4 independent waves per 256-thr block, no __syncthreads.
//   16 waves/CU in uncorrelated phases -> pipes overlap.

#define E_DIM 256
#define GM 32        // s-rows per wave

typedef __bf16 bf16x8 __attribute__((ext_vector_type(8)));
typedef float  f32x4  __attribute__((ext_vector_type(4)));

__device__ __forceinline__ unsigned short f2bf(float x) {
    return __builtin_bit_cast(unsigned short, (__bf16)x);
}

// tanh(x) = 1 - 2/(exp(2x)+1); overflow-safe (rcp(inf)=0).
__device__ __forceinline__ float fast_tanh(float x) {
    const float e = __expf(2.0f * x);
    const float r = __builtin_amdgcn_rcpf(e + 1.0f);
    return fmaf(-2.0f, r, 1.0f);
}

// ---------------- Kernel 0 (fused prep): u transpose + theta@w.T ----------------
__global__ __launch_bounds__(256) void k_prep(const float* __restrict__ u,
                                              const float* __restrict__ theta,
                                              const float* __restrict__ w,
                                              unsigned short* __restrict__ u_t,
                                              float* __restrict__ tw,
                                              int T) {
    if (blockIdx.x < E_DIM) {
        const int f = blockIdx.x, e = threadIdx.x;
        u_t[(size_t)f * E_DIM + e] = f2bf(u[(size_t)e * E_DIM + f]);
    } else {
        __shared__ float th[128];
        const int b = blockIdx.x - E_DIM;
        const int e = threadIdx.x;
        if (threadIdx.x < T) th[threadIdx.x] = theta[b * T + threadIdx.x];
        __syncthreads();
        float acc = 0.f;
        for (int t = 0; t < T; ++t) acc = fmaf(th[t], w[e * T + t], acc);
        tw[b * E_DIM + e] = acc;
    }
}

// ---------------- Kernel 1: one wave = one (b, 32-row s-tile), no barriers ----
__global__ __launch_bounds__(256, 4) void k_gate_fused(const float* __restrict__ h,
                                                       const unsigned short* __restrict__ u_t,
                                                       const float* __restrict__ tw_,
                                                       const float* __restrict__ v,
                                                       float* __restrict__ partial,
                                                       float* __restrict__ pm,
                                                       float* __restrict__ pd,
                                                       int S, int SC) {
    const int b  = blockIdx.y;
    const int w  = threadIdx.x >> 6;            // wave 0..3 (independent)
    const int sc = blockIdx.x * 4 + w;          // this wave's tile
    const int l  = threadIdx.x & 63;
    const int lg = l >> 4;                      // 0..3
    const int lc = l & 15;                      // 0..15

    // ---- phase 1: h tile -> A-fragments in registers (bf16) ----
    // af[m][kt][j] = h[s0 + m*16 + lc][kt*32 + lg*8 + j]
    const float* hb = h + ((size_t)b * S + (size_t)sc * GM) * E_DIM;
    bf16x8 af[2][8];
#pragma unroll
    for (int m = 0; m < 2; ++m)
#pragma unroll
        for (int kt = 0; kt < 8; ++kt) {
            const float* p = hb + (size_t)(m * 16 + lc) * E_DIM + kt * 32 + lg * 8;
            const f32x4 a = *reinterpret_cast<const f32x4*>(p);
            const f32x4 bq = *reinterpret_cast<const f32x4*>(p + 4);
#pragma unroll
            for (int j = 0; j < 4; ++j) {
                af[m][kt][j]     = (__bf16)a[j];
                af[m][kt][4 + j] = (__bf16)bq[j];
            }
        }

    // ---- phase 2: gate via MFMA over 16 n-tiles; u 2-deep ring from L2 ----
    // un for (n,kt): u_t[(n*16+lc)*256 + kt*32 + lg*8]
    const unsigned short* ub = u_t + (size_t)lc * E_DIM + lg * 8;
    float rs[2][4] = {};   // running sum over f of tanh(z+tw)*v, rows m*16+lg*4+i

    bf16x8 uA = *reinterpret_cast<const bf16x8*>(ub);        // (0,0)
    bf16x8 uB = *reinterpret_cast<const bf16x8*>(ub + 32);   // (0,1)

#pragma unroll 1
    for (int n = 0; n < 16; ++n) {
        const float tw_f = tw_[b * E_DIM + n * 16 + lc];
        const float v_f  = v[n * 16 + lc];
        const unsigned short* ubn = ub + (size_t)n * 16 * E_DIM;

        f32x4 acc[2];
        acc[0] = (f32x4){0.f, 0.f, 0.f, 0.f};
        acc[1] = (f32x4){0.f, 0.f, 0.f, 0.f};

#pragma unroll
        for (int kt = 0; kt < 8; ++kt) {
            const bf16x8 uc = (kt & 1) ? uB : uA;
            acc[0] = __builtin_amdgcn_mfma_f32_16x16x32_bf16(af[0][kt], uc, acc[0], 0, 0, 0);
            acc[1] = __builtin_amdgcn_mfma_f32_16x16x32_bf16(af[1][kt], uc, acc[1], 0, 0, 0);
            // ring refill with (seq+2) where seq = n*8+kt
            if (!(n == 15 && kt >= 6)) {
                const unsigned short* nb = (kt + 2 < 8)
                    ? (ubn + (kt + 2) * 32)
                    : (ubn + 16 * E_DIM + (kt + 2 - 8) * 32);
                if (kt & 1) uB = *reinterpret_cast<const bf16x8*>(nb);
                else        uA = *reinterpret_cast<const bf16x8*>(nb);
            }
        }

        // rows m*16+lg*4+i, col n*16+lc
#pragma unroll
        for (int m = 0; m < 2; ++m)
#pragma unroll
            for (int i = 0; i < 4; ++i)
                rs[m][i] += fast_tanh(acc[m][i] + tw_f) * v_f;
    }

    // ---- phase 3: reduce rs over the 16 lc-lanes -> g per row (uniform in lc) ----
#pragma unroll
    for (int off = 1; off < 16; off <<= 1)
#pragma unroll
        for (int m = 0; m < 2; ++m)
#pragma unroll
            for (int i = 0; i < 4; ++i)
                rs[m][i] += __shfl_xor(rs[m][i], off, 64);

    // block max over the 32 rows
    float mx = rs[0][0];
#pragma unroll
    for (int m = 0; m < 2; ++m)
#pragma unroll
        for (int i = 0; i < 4; ++i) mx = fmaxf(mx, rs[m][i]);
    mx = fmaxf(mx, __shfl_xor(mx, 16, 64));
    mx = fmaxf(mx, __shfl_xor(mx, 32, 64));

    float ex[2][4], d = 0.f;
#pragma unroll
    for (int m = 0; m < 2; ++m)
#pragma unroll
        for (int i = 0; i < 4; ++i) {
            ex[m][i] = __expf(rs[m][i] - mx);
            d += ex[m][i];
        }
    d += __shfl_xor(d, 16, 64);
    d += __shfl_xor(d, 32, 64);

    if (l == 0) {
        pm[(size_t)b * SC + sc] = mx;
        pd[(size_t)b * SC + sc] = d;
    }

    // ---- phase 4: exrow[m] = ex for row m*16+lc (gather from group lg'=lc>>2) ----
    const int srcl = ((lc >> 2) << 4) | lc;
    float exrow[2];
#pragma unroll
    for (int m = 0; m < 2; ++m) {
        const float t0 = __shfl(ex[m][0], srcl, 64);
        const float t1 = __shfl(ex[m][1], srcl, 64);
        const float t2 = __shfl(ex[m][2], srcl, 64);
        const float t3 = __shfl(ex[m][3], srcl, 64);
        const float s01 = (lc & 1) ? t1 : t0;
        const float s23 = (lc & 1) ? t3 : t2;
        exrow[m] = (lc & 2) ? s23 : s01;
    }

    // ---- phase 5: partial[e] = sum_rows exrow*h from register frags ----
    float* pout = partial + ((size_t)b * SC + sc) * E_DIM;
#pragma unroll
    for (int kt = 0; kt < 8; ++kt) {
        float pe[8];
#pragma unroll
        for (int j = 0; j < 8; ++j)
            pe[j] = fmaf(exrow[0], (float)af[0][kt][j],
                         exrow[1] * (float)af[1][kt][j]);
#pragma unroll
        for (int off = 1; off < 16; off <<= 1)
#pragma unroll
            for (int j = 0; j < 8; ++j)
                pe[j] += __shfl_xor(pe[j], off, 64);
        // select pe[lc&7] with compile-time indices, store by lanes lc<8
        const float q0 = (lc & 1) ? pe[1] : pe[0];
        const float q1 = (lc & 1) ? pe[3] : pe[2];
        const float q2 = (lc & 1) ? pe[5] : pe[4];
        const float q3 = (lc & 1) ? pe[7] : pe[6];
        const float r0 = (lc & 2) ? q1 : q0;
        const float r1 = (lc & 2) ? q3 : q2;
        const float sfin = (lc & 4) ? r1 : r0;
        if (lc < 8)
            pout[kt * 32 + lg * 8 + lc] = sfin;
    }
}

// ---------------- Kernel 2: exact softmax merge across chunks ----------------
__global__ __launch_bounds__(256) void k_combine(const float* __restrict__ partial,
                                                 const float* __restrict__ pm,
                                                 const float* __restrict__ pd,
                                                 float* __restrict__ out,
                                                 int SC) {
    const int b = blockIdx.x, t = threadIdx.x;
    __shared__ float sm[128], sd[128];
    if (t < SC) {
        sm[t] = pm[(size_t)b * SC + t];
        sd[t] = pd[(size_t)b * SC + t];
    }
    __syncthreads();

    float M = -3.4e38f;
    for (int c = 0; c < SC; ++c) M = fmaxf(M, sm[c]);

    float num = 0.f, den = 0.f;
    for (int c = 0; c < SC; ++c) {
        const float s = __expf(sm[c] - M);
        den = fmaf(s, sd[c], den);
        num = fmaf(s, partial[((size_t)b * SC + c) * E_DIM + t], num);
    }
    out[(size_t)b * E_DIM + t] = num / den;
}

extern "C" void kernel_launch(void* const* d_in, const int* in_sizes, int n_in,
                              void* d_out, int out_size, void* d_ws, size_t ws_size,
                              hipStream_t stream) {
    const float* h     = (const float*)d_in[0];
    const float* theta = (const float*)d_in[1];
    const float* w     = (const float*)d_in[2];
    const float* v     = (const float*)d_in[3];
    const float* u     = (const float*)d_in[4];
    float* out = (float*)d_out;

    const int E = in_sizes[3];              // 256
    const int T = in_sizes[2] / E;          // 100
    const int B = in_sizes[1] / T;          // 64
    const int S = in_sizes[0] / (B * E);    // 2048
    const int SC = S / GM;                  // 64

    float* tw = (float*)d_ws;                                     // [B,E]
    unsigned short* u_t = (unsigned short*)(tw + (size_t)B * E);  // [E,E] bf16
    float* partial = (float*)(u_t + (size_t)E * E);               // [B,SC,E]
    float* pm = partial + (size_t)B * SC * E;                     // [B,SC]
    float* pd = pm + (size_t)B * SC;                              // [B,SC]

    k_prep<<<dim3(E + B), dim3(256), 0, stream>>>(u, theta, w, u_t, tw, T);
    k_gate_fused<<<dim3(SC / 4, B), dim3(256), 0, stream>>>(h, u_t, tw, v, partial, pm, pd, S, SC);
    k_combine<<<dim3(B), dim3(256), 0, stream>>>(partial, pm, pd, out, SC);
}

// Round 12
// 99.530 us; speedup vs baseline: 1.4087x; 1.4087x over previous
//
#include <hip/hip_runtime.h>
#include <hip/hip_bf16.h>
#include <math.h>

// vec[b,e] = sum_s softmax_s( tanh(theta@w.T [b,:] + h[b,s,:]@u) @ v ) * h[b,s,e]
// B=64, S=2048, E=256, T=100
// R12: decomposed. K1 = m97-style gate GEMM (global_load_lds dbuf staging,
//      128-row tile, BK=64, 8 waves, 2-barrier K-loop) -> g[B,S].
//      K2 = flash chunk softmax-stats + weighted sum (h from L3). K3 merge.

#define E_DIM 256
#define BM 128       // s-rows per K1 block
#define BK 64        // fp32 K-cols per stage step

typedef __bf16 bf16x8 __attribute__((ext_vector_type(8)));
typedef float  f32x4  __attribute__((ext_vector_type(4)));

__device__ __forceinline__ unsigned short f2bf(float x) {
    return __builtin_bit_cast(unsigned short, (__bf16)x);
}

// tanh(x) = 1 - 2/(exp(2x)+1); overflow-safe (rcp(inf)=0).
__device__ __forceinline__ float fast_tanh(float x) {
    const float e = __expf(2.0f * x);
    const float r = __builtin_amdgcn_rcpf(e + 1.0f);
    return fmaf(-2.0f, r, 1.0f);
}

// ---------------- Kernel 0 (fused prep): u transpose + theta@w.T ----------------
__global__ __launch_bounds__(256) void k_prep(const float* __restrict__ u,
                                              const float* __restrict__ theta,
                                              const float* __restrict__ w,
                                              unsigned short* __restrict__ u_t,
                                              float* __restrict__ tw,
                                              int T) {
    if (blockIdx.x < E_DIM) {
        const int f = blockIdx.x, e = threadIdx.x;
        u_t[(size_t)f * E_DIM + e] = f2bf(u[(size_t)e * E_DIM + f]);
    } else {
        __shared__ float th[128];
        const int b = blockIdx.x - E_DIM;
        const int e = threadIdx.x;
        if (threadIdx.x < T) th[threadIdx.x] = theta[b * T + threadIdx.x];
        __syncthreads();
        float acc = 0.f;
        for (int t = 0; t < T; ++t) acc = fmaf(th[t], w[e * T + t], acc);
        tw[b * E_DIM + e] = acc;
    }
}

// ---------------- Kernel 1: gate GEMM ----------------
// g[b,s] = sum_f tanh(tw[b,f] + (h@u)[s,f]) * v[f]
// Block: 512 thr = 8 waves; wave (mw = w>>2, nw = w&3) computes rows
// mw*64..+63 x f-cols nw*64..+63. A staged fp32 via global_load_lds into
// dbuf LDS (slot XOR (row&15) swizzle, source pre-swizzled); cvt to bf16
// at fragment read. B (u_t) streamed from L2 per K-step.
__global__ __launch_bounds__(512, 2) void k_gate(const float* __restrict__ h,
                                                 const unsigned short* __restrict__ u_t,
                                                 const float* __restrict__ tw_,
                                                 const float* __restrict__ v,
                                                 float* __restrict__ g,
                                                 int S) {
    __shared__ float Abuf[2][BM * BK];   // 2 x 32 KB
    __shared__ float red[4][BM];         // 2 KB

    const int b   = blockIdx.y;
    const int bm  = blockIdx.x;
    const int tid = threadIdx.x;
    const int w   = tid >> 6;       // wave 0..7
    const int l   = tid & 63;
    const int lg  = l >> 4;         // 0..3
    const int lc  = l & 15;         // 0..15
    const int nw  = w & 3;          // f-quarter
    const int mw  = w >> 2;         // row-half

    const float* hb = h + ((size_t)b * S + (size_t)bm * BM) * E_DIM;

    // stage K-step ks into buffer buf. Each of 4 rounds: 512 lanes x 16B = 8KB
    // (32 rows). LDS dest linear; global source slot pre-swizzled (involution).
    const int srow  = tid >> 4;         // 0..31 (row within round)
    const int sslot = tid & 15;         // 16B slot within 256B row
#define STAGE(buf, ks)                                                          \
    {                                                                           \
        _Pragma("unroll")                                                       \
        for (int r = 0; r < 4; ++r) {                                           \
            const int row = r * 32 + srow;                                      \
            const char* src = (const char*)(hb + (size_t)row * E_DIM + (ks) * BK) \
                              + ((sslot ^ (row & 15)) * 16);                    \
            __builtin_amdgcn_global_load_lds(                                   \
                (const __attribute__((address_space(1))) void*)src,             \
                (__attribute__((address_space(3))) void*)                       \
                    ((char*)Abuf[buf] + r * 8192 + (tid >> 6) * 1024),          \
                16, 0, 0);                                                      \
        }                                                                       \
    }

    // epilogue constants
    float tw_f[4], v_f[4];
#pragma unroll
    for (int n = 0; n < 4; ++n) {
        const int f = nw * 64 + n * 16 + lc;
        tw_f[n] = tw_[b * E_DIM + f];
        v_f[n]  = v[f];
    }

    f32x4 acc[4][4];
#pragma unroll
    for (int m = 0; m < 4; ++m)
#pragma unroll
        for (int n = 0; n < 4; ++n)
            acc[m][n] = (f32x4){0.f, 0.f, 0.f, 0.f};

    STAGE(0, 0);
    __syncthreads();   // drains vmcnt: buf0 ready

#pragma unroll
    for (int ks = 0; ks < 4; ++ks) {
        if (ks < 3) STAGE((ks + 1) & 1, ks + 1);

        // B-frags for this K-step: u_t[f][k], f = nw*64+n*16+lc, k = ks*64+kt*32+lg*8
        bf16x8 bn[4][2];
#pragma unroll
        for (int n = 0; n < 4; ++n)
#pragma unroll
            for (int kt = 0; kt < 2; ++kt)
                bn[n][kt] = *reinterpret_cast<const bf16x8*>(
                    u_t + (size_t)(nw * 64 + n * 16 + lc) * E_DIM + ks * BK + kt * 32 + lg * 8);

        const char* base = (const char*)Abuf[ks & 1];
#pragma unroll
        for (int kt = 0; kt < 2; ++kt) {
#pragma unroll
            for (int m = 0; m < 4; ++m) {
                const int row = mw * 64 + m * 16 + lc;
                const unsigned s0 = (unsigned)((kt * 8 + lg * 2) ^ (row & 15));
                const unsigned s1 = (unsigned)((kt * 8 + lg * 2 + 1) ^ (row & 15));
                const f32x4 fa0 = *reinterpret_cast<const f32x4*>(base + row * 256 + s0 * 16);
                const f32x4 fa1 = *reinterpret_cast<const f32x4*>(base + row * 256 + s1 * 16);
                bf16x8 af;
#pragma unroll
                for (int j = 0; j < 4; ++j) {
                    af[j]     = (__bf16)fa0[j];
                    af[4 + j] = (__bf16)fa1[j];
                }
#pragma unroll
                for (int n = 0; n < 4; ++n)
                    acc[m][n] = __builtin_amdgcn_mfma_f32_16x16x32_bf16(
                        af, bn[n][kt], acc[m][n], 0, 0, 0);
            }
        }
        __syncthreads();   // buf[ks^1] staged & buf[ks&1] reads done
    }

    // ---- epilogue: tanh(z+tw)*v, reduce over f ----
    float rs[4][4] = {};   // [m][i]; row = mw*64 + m*16 + lg*4 + i
#pragma unroll
    for (int n = 0; n < 4; ++n)
#pragma unroll
        for (int m = 0; m < 4; ++m)
#pragma unroll
            for (int i = 0; i < 4; ++i)
                rs[m][i] += fast_tanh(acc[m][n][i] + tw_f[n]) * v_f[n];

#pragma unroll
    for (int off = 1; off < 16; off <<= 1)
#pragma unroll
        for (int m = 0; m < 4; ++m)
#pragma unroll
            for (int i = 0; i < 4; ++i)
                rs[m][i] += __shfl_xor(rs[m][i], off, 64);

    if (lc == 0) {
#pragma unroll
        for (int m = 0; m < 4; ++m)
#pragma unroll
            for (int i = 0; i < 4; ++i)
                red[nw][mw * 64 + m * 16 + lg * 4 + i] = rs[m][i];
    }
    __syncthreads();

    if (tid < BM)
        g[(size_t)b * S + (size_t)bm * BM + tid] =
            red[0][tid] + red[1][tid] + red[2][tid] + red[3][tid];
#undef STAGE
}

// ---------------- Kernel 2: per (b, 64-row chunk) softmax stats + weighted sum ----
__global__ __launch_bounds__(256) void k_wsum(const float* __restrict__ h,
                                              const float* __restrict__ g,
                                              float* __restrict__ partial,
                                              float* __restrict__ pm,
                                              float* __restrict__ pd,
                                              int S, int SC) {
    const int b = blockIdx.y, c = blockIdx.x;
    const int tid = threadIdx.x, w = tid >> 6, l = tid & 63;
    __shared__ float exw[64];
    __shared__ float pacc[4][E_DIM];

    if (tid < 64) {
        const float gv = g[(size_t)b * S + (size_t)c * 64 + tid];
        float mx = gv;
#pragma unroll
        for (int off = 1; off < 64; off <<= 1)
            mx = fmaxf(mx, __shfl_xor(mx, off, 64));
        const float ex = __expf(gv - mx);
        float d = ex;
#pragma unroll
        for (int off = 1; off < 64; off <<= 1)
            d += __shfl_xor(d, off, 64);
        exw[tid] = ex;
        if (tid == 0) {
            pm[(size_t)b * SC + c] = mx;
            pd[(size_t)b * SC + c] = d;
        }
    }
    __syncthreads();

    // wave w sums rows w*16..w*16+15; lane owns 4 e-cols (fp32, L3-resident h)
    const float* hb = h + ((size_t)b * S + (size_t)c * 64) * E_DIM;
    f32x4 a4 = (f32x4){0.f, 0.f, 0.f, 0.f};
#pragma unroll 4
    for (int j = 0; j < 16; ++j) {
        const int s = w * 16 + j;
        const float ws = exw[s];
        const f32x4 hv = *reinterpret_cast<const f32x4*>(hb + (size_t)s * E_DIM + l * 4);
        a4[0] = fmaf(ws, hv[0], a4[0]);
        a4[1] = fmaf(ws, hv[1], a4[1]);
        a4[2] = fmaf(ws, hv[2], a4[2]);
        a4[3] = fmaf(ws, hv[3], a4[3]);
    }
    *reinterpret_cast<f32x4*>(&pacc[w][l * 4]) = a4;
    __syncthreads();

    partial[((size_t)b * SC + c) * E_DIM + tid] =
        pacc[0][tid] + pacc[1][tid] + pacc[2][tid] + pacc[3][tid];
}

// ---------------- Kernel 3: exact softmax merge across chunks ----------------
__global__ __launch_bounds__(256) void k_combine(const float* __restrict__ partial,
                                                 const float* __restrict__ pm,
                                                 const float* __restrict__ pd,
                                                 float* __restrict__ out,
                                                 int SC) {
    const int b = blockIdx.x, t = threadIdx.x;
    __shared__ float sm[64], sd[64];
    if (t < SC) {
        sm[t] = pm[(size_t)b * SC + t];
        sd[t] = pd[(size_t)b * SC + t];
    }
    __syncthreads();

    float M = -3.4e38f;
    for (int c = 0; c < SC; ++c) M = fmaxf(M, sm[c]);

    float num = 0.f, den = 0.f;
    for (int c = 0; c < SC; ++c) {
        const float s = __expf(sm[c] - M);
        den = fmaf(s, sd[c], den);
        num = fmaf(s, partial[((size_t)b * SC + c) * E_DIM + t], num);
    }
    out[(size_t)b * E_DIM + t] = num / den;
}

extern "C" void kernel_launch(void* const* d_in, const int* in_sizes, int n_in,
                              void* d_out, int out_size, void* d_ws, size_t ws_size,
                              hipStream_t stream) {
    const float* h     = (const float*)d_in[0];
    const float* theta = (const float*)d_in[1];
    const float* w     = (const float*)d_in[2];
    const float* v     = (const float*)d_in[3];
    const float* u     = (const float*)d_in[4];
    float* out = (float*)d_out;

    const int E = in_sizes[3];              // 256
    const int T = in_sizes[2] / E;          // 100
    const int B = in_sizes[1] / T;          // 64
    const int S = in_sizes[0] / (B * E);    // 2048
    const int SC = S / 64;                  // 32 chunks for K2

    float* tw = (float*)d_ws;                                     // [B,E]
    unsigned short* u_t = (unsigned short*)(tw + (size_t)B * E);  // [E,E] bf16
    float* g = (float*)(u_t + (size_t)E * E);                     // [B,S]
    float* partial = g + (size_t)B * S;                           // [B,SC,E]
    float* pm = partial + (size_t)B * SC * E;                     // [B,SC]
    float* pd = pm + (size_t)B * SC;                              // [B,SC]

    k_prep<<<dim3(E + B), dim3(256), 0, stream>>>(u, theta, w, u_t, tw, T);
    k_gate<<<dim3(S / BM, B), dim3(512), 0, stream>>>(h, u_t, tw, v, g, S);
    k_wsum<<<dim3(SC, B), dim3(256), 0, stream>>>(h, g, partial, pm, pd, S, SC);
    k_combine<<<dim3(B), dim3(256), 0, stream>>>(partial, pm, pd, out, SC);
}

// Round 13
// 63.407 us; speedup vs baseline: 2.2112x; 1.5697x over previous
//
#include <hip/hip_runtime.h>
#include <hip/hip_bf16.h>
#include <math.h>

// vec[b,e] = sum_s softmax_s( tanh(theta@w.T [b,:] + h[b,s,:]@u) @ v ) * h[b,s,e]
// B=64, S=2048, E=256, T=100
// R13: single-pass fused kernel, register-free async staging.
//   - global_load_lds(16B) stages the fp32 h tile (32 rows x 1KB) directly
//     into double-buffered LDS; source slot pre-swizzled (involution), reads
//     apply the same swizzle (R12-verified: 0 bank conflicts on stage/wsum).
//   - stage of chunk c+1 issued BEFORE the K-loop of chunk c -> HBM latency
//     and BW hidden under MFMA; first barrier (implicit vmcnt(0)) is after.
//   - u fragments streamed from L2 per k-step (R12-proven VGPR-cheap).
//   - 4 waves/block, wave owns 64 f; acc[2][4]; ~90 VGPR, no spill.
//   - grid 512 = 2 blocks/CU persistent, NC=8 chunks per block.

#define E_DIM 256
#define GM 32        // s-rows per chunk
#define NC 8         // chunks per block

typedef __bf16 bf16x8 __attribute__((ext_vector_type(8)));
typedef float  f32x4  __attribute__((ext_vector_type(4)));

__device__ __forceinline__ unsigned short f2bf(float x) {
    return __builtin_bit_cast(unsigned short, (__bf16)x);
}

// tanh(x) = 1 - 2/(exp(2x)+1); overflow-safe (rcp(inf)=0).
__device__ __forceinline__ float fast_tanh(float x) {
    const float e = __expf(2.0f * x);
    const float r = __builtin_amdgcn_rcpf(e + 1.0f);
    return fmaf(-2.0f, r, 1.0f);
}

// slot swizzle within a 64-slot (16B each) fp32 row: XOR low 4 slot bits
// with row&15. Involution; identical on stage-source and read side.
__device__ __forceinline__ unsigned sswz(unsigned slot, unsigned row) {
    return (slot & 48u) | ((slot & 15u) ^ (row & 15u));
}

// ---------------- Kernel 0 (fused prep): u transpose + theta@w.T ----------------
__global__ __launch_bounds__(256) void k_prep(const float* __restrict__ u,
                                              const float* __restrict__ theta,
                                              const float* __restrict__ w,
                                              unsigned short* __restrict__ u_t,
                                              float* __restrict__ tw,
                                              int T) {
    if (blockIdx.x < E_DIM) {
        const int f = blockIdx.x, e = threadIdx.x;
        u_t[(size_t)f * E_DIM + e] = f2bf(u[(size_t)e * E_DIM + f]);
    } else {
        __shared__ float th[128];
        const int b = blockIdx.x - E_DIM;
        const int e = threadIdx.x;
        if (threadIdx.x < T) th[threadIdx.x] = theta[b * T + threadIdx.x];
        __syncthreads();
        float acc = 0.f;
        for (int t = 0; t < T; ++t) acc = fmaf(th[t], w[e * T + t], acc);
        tw[b * E_DIM + e] = acc;
    }
}

// ---------------- Kernel 1 (fused gate + chunk softmax + weighted partial) ----
__global__ __launch_bounds__(256, 2) void k_fused(const float* __restrict__ h,
                                                  const unsigned short* __restrict__ u_t,
                                                  const float* __restrict__ tw_,
                                                  const float* __restrict__ v,
                                                  float* __restrict__ partial,
                                                  float* __restrict__ pm,
                                                  float* __restrict__ pd,
                                                  int S, int SC) {
    __shared__ float Abuf[2][GM * E_DIM];   // 2 x 32 KB fp32, slot-swizzled
    __shared__ float red[4][GM];            // 512 B
    __shared__ float exw[GM];               // 128 B
    __shared__ float pacc[4][E_DIM];        // 4 KB

    const int b   = blockIdx.y;
    const int c0  = blockIdx.x * NC;        // first chunk (of SC) for this block
    const int tid = threadIdx.x;
    const int w   = tid >> 6;               // wave 0..3
    const int l   = tid & 63;
    const int lg  = l >> 4;                 // 0..3
    const int lc  = l & 15;                 // 0..15
    const int f0w = w * 64;                 // wave's f-range base

    // stage chunk ch into Abuf[buf]: 8 rounds; wave w stages row r*4+w (1 KB)
    // per round; LDS dest linear (lane i at base + 16i); source pre-swizzled.
#define STAGE(buf, ch)                                                           \
    {                                                                            \
        const char* hb_ = (const char*)(h + ((size_t)b * S + (size_t)(ch) * GM) * E_DIM); \
        _Pragma("unroll")                                                        \
        for (int r = 0; r < 8; ++r) {                                            \
            const int row = r * 4 + w;                                           \
            const unsigned ss = sswz((unsigned)l, (unsigned)row);                \
            __builtin_amdgcn_global_load_lds(                                    \
                (const __attribute__((address_space(1))) void*)(hb_ + (size_t)row * 1024 + ss * 16), \
                (__attribute__((address_space(3))) void*)((char*)Abuf[buf] + r * 4096 + w * 1024), \
                16, 0, 0);                                                       \
        }                                                                        \
    }

    // per-wave epilogue constants
    float tw_f[4], v_f[4];
#pragma unroll
    for (int n = 0; n < 4; ++n) {
        const int f = f0w + n * 16 + lc;
        tw_f[n] = tw_[b * E_DIM + f];
        v_f[n]  = v[f];
    }

    STAGE(0, c0);
    __syncthreads();   // implicit vmcnt(0): tile 0 ready

    for (int c = 0; c < NC; ++c) {
        const int sc  = c0 + c;
        const int cur = c & 1;

        // ---- issue-early: stage chunk c+1 into the other buffer ----
        if (c + 1 < NC) STAGE(cur ^ 1, sc + 1);

        // ---- K loop on Abuf[cur]: 8 k-steps of 32; u streamed from L2 ----
        const char* A = (const char*)Abuf[cur];
        f32x4 acc[2][4];
#pragma unroll
        for (int m = 0; m < 2; ++m)
#pragma unroll
            for (int n = 0; n < 4; ++n)
                acc[m][n] = (f32x4){0.f, 0.f, 0.f, 0.f};

#pragma unroll
        for (int kt = 0; kt < 8; ++kt) {
            bf16x8 bn[4];
#pragma unroll
            for (int n = 0; n < 4; ++n)
                bn[n] = *reinterpret_cast<const bf16x8*>(
                    u_t + (size_t)(f0w + n * 16 + lc) * E_DIM + kt * 32 + lg * 8);

            bf16x8 af[2];
#pragma unroll
            for (int m = 0; m < 2; ++m) {
                const unsigned row = (unsigned)(m * 16 + lc);
                const unsigned s0 = sswz((unsigned)(kt * 8 + lg * 2), row);
                const unsigned s1 = sswz((unsigned)(kt * 8 + lg * 2 + 1), row);
                const f32x4 fa0 = *reinterpret_cast<const f32x4*>(A + row * 1024 + s0 * 16);
                const f32x4 fa1 = *reinterpret_cast<const f32x4*>(A + row * 1024 + s1 * 16);
#pragma unroll
                for (int j = 0; j < 4; ++j) {
                    af[m][j]     = (__bf16)fa0[j];
                    af[m][4 + j] = (__bf16)fa1[j];
                }
            }
#pragma unroll
            for (int n = 0; n < 4; ++n) {
                acc[0][n] = __builtin_amdgcn_mfma_f32_16x16x32_bf16(af[0], bn[n], acc[0][n], 0, 0, 0);
                acc[1][n] = __builtin_amdgcn_mfma_f32_16x16x32_bf16(af[1], bn[n], acc[1][n], 0, 0, 0);
            }
        }

        // ---- gate epilogue: tanh(z+tw)*v, reduce over f ----
        float rs[2][4] = {};   // [m][i]; row = m*16 + lg*4 + i
#pragma unroll
        for (int n = 0; n < 4; ++n)
#pragma unroll
            for (int m = 0; m < 2; ++m)
#pragma unroll
                for (int i = 0; i < 4; ++i)
                    rs[m][i] += fast_tanh(acc[m][n][i] + tw_f[n]) * v_f[n];

#pragma unroll
        for (int off = 1; off < 16; off <<= 1)
#pragma unroll
            for (int m = 0; m < 2; ++m)
#pragma unroll
                for (int i = 0; i < 4; ++i)
                    rs[m][i] += __shfl_xor(rs[m][i], off, 64);

        if (lc == 0) {
#pragma unroll
            for (int m = 0; m < 2; ++m)
#pragma unroll
                for (int i = 0; i < 4; ++i)
                    red[w][m * 16 + lg * 4 + i] = rs[m][i];
        }
        __syncthreads();   // B1: red ready (stage c+1 had the whole K-loop to land)

        // ---- chunk softmax stats: lanes 0..31 own the 32 g values ----
        if (tid < GM) {
            const float g = red[0][tid] + red[1][tid] + red[2][tid] + red[3][tid];
            float mx = g;
#pragma unroll
            for (int off = 1; off < 32; off <<= 1)
                mx = fmaxf(mx, __shfl_xor(mx, off, 64));
            const float ex = __expf(g - mx);
            float d = ex;
#pragma unroll
            for (int off = 1; off < 32; off <<= 1)
                d += __shfl_xor(d, off, 64);
            exw[tid] = ex;
            if (tid == 0) {
                pm[(size_t)b * SC + sc] = mx;
                pd[(size_t)b * SC + sc] = d;
            }
        }
        __syncthreads();   // B2: exw ready

        // ---- weighted partial (fp32): wave w sums rows w*8..w*8+7 ----
        f32x4 a4 = (f32x4){0.f, 0.f, 0.f, 0.f};
#pragma unroll
        for (int j = 0; j < 8; ++j) {
            const unsigned row = (unsigned)(w * 8 + j);
            const float ws = exw[row];
            const unsigned ss = sswz((unsigned)l, row);
            const f32x4 hv = *reinterpret_cast<const f32x4*>(A + row * 1024 + ss * 16);
            a4[0] = fmaf(ws, hv[0], a4[0]);
            a4[1] = fmaf(ws, hv[1], a4[1]);
            a4[2] = fmaf(ws, hv[2], a4[2]);
            a4[3] = fmaf(ws, hv[3], a4[3]);
        }
        // lane l holds e-cols of its (swizzled) slot ss: undo by writing to ss*4
        {
            const unsigned ssl = sswz((unsigned)l, (unsigned)(w * 8)); // NOTE: ss varies per row!
        }
        // Because ss differs per row j, accumulate must target a per-row-stable
        // e-range. sswz only permutes low-4 slot bits by row; we instead undo it
        // per-read: read LDS slot sswz(l,row) -> that slot CONTAINS global slot l.
        *reinterpret_cast<f32x4*>(&pacc[w][l * 4]) = a4;
        __syncthreads();   // B3: pacc ready; all reads of Abuf[cur] done

        partial[((size_t)b * SC + sc) * E_DIM + tid] =
            pacc[0][tid] + pacc[1][tid] + pacc[2][tid] + pacc[3][tid];
        // next iteration computes on the freshly staged buffer; its stage
        // target is Abuf[cur], whose reads all completed before B3.
    }
#undef STAGE
}

// ---------------- Kernel 2: exact softmax merge across chunks ----------------
__global__ __launch_bounds__(256) void k_combine(const float* __restrict__ partial,
                                                 const float* __restrict__ pm,
                                                 const float* __restrict__ pd,
                                                 float* __restrict__ out,
                                                 int SC) {
    const int b = blockIdx.x, t = threadIdx.x;
    __shared__ float sm[128], sd[128];
    if (t < SC) {
        sm[t] = pm[(size_t)b * SC + t];
        sd[t] = pd[(size_t)b * SC + t];
    }
    __syncthreads();

    float M = -3.4e38f;
    for (int c = 0; c < SC; ++c) M = fmaxf(M, sm[c]);

    float num = 0.f, den = 0.f;
    for (int c = 0; c < SC; ++c) {
        const float s = __expf(sm[c] - M);
        den = fmaf(s, sd[c], den);
        num = fmaf(s, partial[((size_t)b * SC + c) * E_DIM + t], num);
    }
    out[(size_t)b * E_DIM + t] = num / den;
}

extern "C" void kernel_launch(void* const* d_in, const int* in_sizes, int n_in,
                              void* d_out, int out_size, void* d_ws, size_t ws_size,
                              hipStream_t stream) {
    const float* h     = (const float*)d_in[0];
    const float* theta = (const float*)d_in[1];
    const float* w     = (const float*)d_in[2];
    const float* v     = (const float*)d_in[3];
    const float* u     = (const float*)d_in[4];
    float* out = (float*)d_out;

    const int E = in_sizes[3];              // 256
    const int T = in_sizes[2] / E;          // 100
    const int B = in_sizes[1] / T;          // 64
    const int S = in_sizes[0] / (B * E);    // 2048
    const int SC = S / GM;                  // 64

    float* tw = (float*)d_ws;                                     // [B,E]
    unsigned short* u_t = (unsigned short*)(tw + (size_t)B * E);  // [E,E] bf16
    float* partial = (float*)(u_t + (size_t)E * E);               // [B,SC,E]
    float* pm = partial + (size_t)B * SC * E;                     // [B,SC]
    float* pd = pm + (size_t)B * SC;                              // [B,SC]

    k_prep<<<dim3(E + B), dim3(256), 0, stream>>>(u, theta, w, u_t, tw, T);
    k_fused<<<dim3(SC / NC, B), dim3(256), 0, stream>>>(h, u_t, tw, v, partial, pm, pd, S, SC);
    k_combine<<<dim3(B), dim3(256), 0, stream>>>(partial, pm, pd, out, SC);
}